// Round 5
// baseline (215.897 us; speedup 1.0000x reference)
//
#include <hip/hip_runtime.h>

#define FD 128
#define BCAP 8192
typedef __attribute__((ext_vector_type(8))) short short8;
typedef __attribute__((ext_vector_type(4))) float f32x4;

static __device__ __forceinline__ unsigned short f2b(float f) {
    unsigned u = __builtin_bit_cast(unsigned, f);
    unsigned r = (u + 0x7FFFu + ((u >> 16) & 1u)) >> 16;
    return (unsigned short)r;
}
static __device__ __forceinline__ float b2f(unsigned short h) {
    unsigned u = ((unsigned)h) << 16;
    return __builtin_bit_cast(float, u);
}

// edge accessors handling either int32 or int64 storage of (2,E) edge_index.
// int64 values fit in 32 bits -> load only the low word.
static __device__ __forceinline__ int edgeDst(const void* ei, int e, int E, int i32) {
    if (i32) return ((const int*)ei)[E + e];
    return ((const int*)ei)[2 * (E + e)];
}
static __device__ __forceinline__ int2 edgePair(const void* ei, int e, int E, int i32) {
    if (i32) { const int* p = (const int*)ei; return make_int2(p[e], p[E + e]); }
    const int* p = (const int*)ei;
    return make_int2(p[2 * e], p[2 * (E + e)]);
}

// ---------- prep: detect dtype + zero gcur | f32->bf16 cvt | weight repack ----------
__global__ __launch_bounds__(256) void prep_k(
        const unsigned int* __restrict__ ei, int* __restrict__ flag, int* __restrict__ gcur,
        const float* __restrict__ x, unsigned short* __restrict__ xb, int n4,
        const float* __restrict__ Wa, const float* __restrict__ Wb,
        const float* __restrict__ Wc, const float* __restrict__ Wd,
        const float* __restrict__ We, const float* __restrict__ Wf,
        unsigned short* __restrict__ P0, int nCvt, int E) {
    int b = blockIdx.x;
    int t = threadIdx.x;
    if (b < nCvt) {
        int i = b * 256 + t;
        if (i < n4) {
            float4 v = ((const float4*)x)[i];
            unsigned long long o = (unsigned long long)f2b(v.x)
                                 | ((unsigned long long)f2b(v.y) << 16)
                                 | ((unsigned long long)f2b(v.z) << 32)
                                 | ((unsigned long long)f2b(v.w) << 48);
            ((unsigned long long*)xb)[i] = o;
        }
    } else if (b < nCvt + 384) {
        int pb = b - nCvt;
        int which = pb >> 6;
        const float* W = which == 0 ? Wa : which == 1 ? Wb : which == 2 ? Wc
                       : which == 3 ? Wd : which == 4 ? We : Wf;
        unsigned short* P = P0 + (size_t)which * FD * FD;
        int i = (pb & 63) * 256 + t;
        int n = i >> 7, k = i & 127;
        P[(((k >> 3) * FD) + n) * 8 + (k & 7)] = f2b(W[n * FD + k]);
    } else {
        gcur[t] = 0;
        __shared__ int any;
        if (t == 0) any = 0;
        __syncthreads();
        int samples = 2048;
        if (samples > E) samples = E;
        for (int i = t; i < samples; i += 256)
            if (ei[2 * i + 1] != 0u) any = 1;
        __syncthreads();
        if (t == 0) *flag = any;   // any!=0 -> int32 data
    }
}

// ---------- bin edges into fixed-capacity bucket regions (bucket = dst>>8) ----------
__global__ __launch_bounds__(512) void bin_k(const void* __restrict__ ei,
                                             const int* __restrict__ flag,
                                             int* __restrict__ gcur,
                                             int2* __restrict__ binned, int E) {
    __shared__ int h[256];
    __shared__ int gb[256];
    __shared__ int lc[256];
    int t = threadIdx.x;
    if (t < 256) { h[t] = 0; lc[t] = 0; }
    __syncthreads();
    int i32 = *flag;
    int base = blockIdx.x * 8192;
#pragma unroll
    for (int i = 0; i < 16; ++i) {
        int e = base + i * 512 + t;
        if (e < E) atomicAdd(&h[edgeDst(ei, e, E, i32) >> 8], 1);
    }
    __syncthreads();
    if (t < 256 && h[t]) gb[t] = atomicAdd(&gcur[t], h[t]);
    __syncthreads();
#pragma unroll
    for (int i = 0; i < 16; ++i) {
        int e = base + i * 512 + t;
        if (e < E) {
            int2 p = edgePair(ei, e, E, i32);
            int bk = p.y >> 8;
            int r = atomicAdd(&lc[bk], 1);
            binned[(size_t)bk * BCAP + gb[bk] + r] = p;
        }
    }
}

// ---------- per-bucket CSR: rp/rend + srcs (bucketed layout, block-local writes) ----------
__global__ __launch_bounds__(256) void csr_k(const int2* __restrict__ binned,
                                             const int* __restrict__ gcur,
                                             int* __restrict__ rp, int* __restrict__ rend,
                                             int* __restrict__ srcs, int N) {
    __shared__ int h[256];
    __shared__ int cur[256];
    int t = threadIdx.x;
    int b = blockIdx.x;
    int base = b * BCAP;
    int cnt = gcur[b];
    int n0 = b << 8;
    h[t] = 0;
    __syncthreads();
    for (int i = t; i < cnt; i += 256)
        atomicAdd(&h[binned[base + i].y - n0], 1);
    __syncthreads();
    int v = h[t];
    for (int off = 1; off < 256; off <<= 1) {
        int add = (t >= off) ? h[t - off] : 0;
        __syncthreads();
        h[t] += add;
        __syncthreads();
    }
    int excl = h[t] - v;
    int n = n0 + t;
    if (n < N) { rp[n] = base + excl; rend[n] = base + excl + v; }
    cur[t] = base + excl;
    __syncthreads();
    for (int i = t; i < cnt; i += 256) {
        int2 p = binned[base + i];
        int pos = atomicAdd(&cur[p.y - n0], 1);
        srcs[pos] = p.x;
    }
}

// ---------- fused layer: aggregate 64 nodes into LDS, then MFMA GEMM ----------
// out = [agg | hin] @ [Wrel;Wroot]^T + b  (optional ReLU)
template <int OUT_BF16>
__global__ __launch_bounds__(256) void fused_k(
        const unsigned short* __restrict__ hb,
        const int* __restrict__ rp, const int* __restrict__ rend,
        const int* __restrict__ srcs,
        const unsigned short* __restrict__ BpRel, const unsigned short* __restrict__ BpRoot,
        const float* __restrict__ bias, void* __restrict__ outp, int N, int relu) {
    __shared__ unsigned short sagg[64 * FD];   // 16 KB, rows XOR-swizzled
    int wid = threadIdx.x >> 6, lane = threadIdx.x & 63;
    int g = lane >> 4, c = lane & 15;
    int b0 = blockIdx.x * 64;

    // ---- phase 1: per-wave aggregation of 16 nodes each ----
    const unsigned short* hbc = hb + c * 8;
    for (int i = 0; i < 16; ++i) {
        int nd = wid * 16 + i;
        int node = b0 + nd;
        float a[8];
#pragma unroll
        for (int j = 0; j < 8; ++j) a[j] = 0.f;
        if (node < N) {
            int idx = rp[node] + g;
            int e1 = rend[node];
            for (; idx + 4 < e1; idx += 8) {
                int s0 = srcs[idx];
                int s1 = srcs[idx + 4];
                uint4 v0 = *(const uint4*)(hbc + (size_t)s0 * FD);
                uint4 v1 = *(const uint4*)(hbc + (size_t)s1 * FD);
                a[0] += b2f((unsigned short)(v0.x & 0xFFFF)) + b2f((unsigned short)(v1.x & 0xFFFF));
                a[1] += b2f((unsigned short)(v0.x >> 16))    + b2f((unsigned short)(v1.x >> 16));
                a[2] += b2f((unsigned short)(v0.y & 0xFFFF)) + b2f((unsigned short)(v1.y & 0xFFFF));
                a[3] += b2f((unsigned short)(v0.y >> 16))    + b2f((unsigned short)(v1.y >> 16));
                a[4] += b2f((unsigned short)(v0.z & 0xFFFF)) + b2f((unsigned short)(v1.z & 0xFFFF));
                a[5] += b2f((unsigned short)(v0.z >> 16))    + b2f((unsigned short)(v1.z >> 16));
                a[6] += b2f((unsigned short)(v0.w & 0xFFFF)) + b2f((unsigned short)(v1.w & 0xFFFF));
                a[7] += b2f((unsigned short)(v0.w >> 16))    + b2f((unsigned short)(v1.w >> 16));
            }
            if (idx < e1) {
                int s0 = srcs[idx];
                uint4 v0 = *(const uint4*)(hbc + (size_t)s0 * FD);
                a[0] += b2f((unsigned short)(v0.x & 0xFFFF));
                a[1] += b2f((unsigned short)(v0.x >> 16));
                a[2] += b2f((unsigned short)(v0.y & 0xFFFF));
                a[3] += b2f((unsigned short)(v0.y >> 16));
                a[4] += b2f((unsigned short)(v0.z & 0xFFFF));
                a[5] += b2f((unsigned short)(v0.z >> 16));
                a[6] += b2f((unsigned short)(v0.w & 0xFFFF));
                a[7] += b2f((unsigned short)(v0.w >> 16));
            }
        }
#pragma unroll
        for (int j = 0; j < 8; ++j) {
            a[j] += __shfl_xor(a[j], 16);
            a[j] += __shfl_xor(a[j], 32);
        }
        if (lane < 16) {
            uint4 o;
            o.x = (unsigned)f2b(a[0]) | ((unsigned)f2b(a[1]) << 16);
            o.y = (unsigned)f2b(a[2]) | ((unsigned)f2b(a[3]) << 16);
            o.z = (unsigned)f2b(a[4]) | ((unsigned)f2b(a[5]) << 16);
            o.w = (unsigned)f2b(a[6]) | ((unsigned)f2b(a[7]) << 16);
            int byteoff = nd * 256 + ((c * 16) ^ ((nd & 7) << 4));
            *(uint4*)((char*)sagg + byteoff) = o;
        }
    }
    __syncthreads();

    // ---- phase 2: MFMA ----
    int l15 = lane & 15, lhi = lane >> 4;
    int n0 = wid * 32;

    f32x4 acc[4][2];
#pragma unroll
    for (int r = 0; r < 4; ++r)
#pragma unroll
        for (int t = 0; t < 2; ++t) acc[r][t] = (f32x4){0.f, 0.f, 0.f, 0.f};

    // rel half: A from LDS (swizzled)
#pragma unroll
    for (int kk = 0; kk < 4; ++kk) {
        short8 bf0 = *(const short8*)(BpRel + (((kk * 4 + lhi) * FD) + n0 + l15) * 8);
        short8 bf1 = *(const short8*)(BpRel + (((kk * 4 + lhi) * FD) + n0 + 16 + l15) * 8);
        int bc = kk * 64 + lhi * 16;
#pragma unroll
        for (int r = 0; r < 4; ++r) {
            int rr = r * 16 + l15;
            short8 af = *(const short8*)((const char*)sagg + rr * 256 + (bc ^ ((rr & 7) << 4)));
            acc[r][0] = __builtin_amdgcn_mfma_f32_16x16x32_bf16(af, bf0, acc[r][0], 0, 0, 0);
            acc[r][1] = __builtin_amdgcn_mfma_f32_16x16x32_bf16(af, bf1, acc[r][1], 0, 0, 0);
        }
    }
    // root half: A from global
#pragma unroll
    for (int kk = 0; kk < 4; ++kk) {
        short8 bf0 = *(const short8*)(BpRoot + (((kk * 4 + lhi) * FD) + n0 + l15) * 8);
        short8 bf1 = *(const short8*)(BpRoot + (((kk * 4 + lhi) * FD) + n0 + 16 + l15) * 8);
#pragma unroll
        for (int r = 0; r < 4; ++r) {
            int row = b0 + r * 16 + l15;
            if (row >= N) row = N - 1;
            short8 af = *(const short8*)(hb + (size_t)row * FD + kk * 32 + lhi * 8);
            acc[r][0] = __builtin_amdgcn_mfma_f32_16x16x32_bf16(af, bf0, acc[r][0], 0, 0, 0);
            acc[r][1] = __builtin_amdgcn_mfma_f32_16x16x32_bf16(af, bf1, acc[r][1], 0, 0, 0);
        }
    }

    float bb0 = bias[n0 + l15];
    float bb1 = bias[n0 + 16 + l15];
#pragma unroll
    for (int r = 0; r < 4; ++r) {
#pragma unroll
        for (int t = 0; t < 2; ++t) {
            int col = n0 + t * 16 + l15;
            float bb = t ? bb1 : bb0;
#pragma unroll
            for (int j = 0; j < 4; ++j) {
                int row = b0 + r * 16 + lhi * 4 + j;
                if (row < N) {
                    float v = acc[r][t][j] + bb;
                    if (relu) v = fmaxf(v, 0.f);
                    if (OUT_BF16)
                        ((unsigned short*)outp)[(size_t)row * FD + col] = f2b(v);
                    else
                        ((float*)outp)[(size_t)row * FD + col] = v;
                }
            }
        }
    }
}

extern "C" void kernel_launch(void* const* d_in, const int* in_sizes, int n_in,
                              void* d_out, int out_size, void* d_ws, size_t ws_size,
                              hipStream_t stream) {
    const float* x   = (const float*)d_in[0];
    const float* W1r = (const float*)d_in[2];
    const float* b1  = (const float*)d_in[3];
    const float* W1o = (const float*)d_in[4];
    const float* W2r = (const float*)d_in[5];
    const float* b2  = (const float*)d_in[6];
    const float* W2o = (const float*)d_in[7];
    const float* W3r = (const float*)d_in[8];
    const float* b3  = (const float*)d_in[9];
    const float* W3o = (const float*)d_in[10];

    int N = in_sizes[0] / FD;
    int E = in_sizes[1] / 2;
    int NB = (N + 255) >> 8;   // buckets of 256 nodes

    char* ws = (char*)d_ws;
    size_t off = 0;
    auto alloc = [&](size_t bytes) -> void* {
        void* p = ws + off;
        off = (off + bytes + 255) & ~(size_t)255;
        return p;
    };
    int*  flag   = (int*)alloc(4);
    int*  gcur   = (int*)alloc(256 * 4);
    int*  rp     = (int*)alloc((size_t)N * 4);
    int*  rend   = (int*)alloc((size_t)N * 4);
    int*  srcs   = (int*)alloc((size_t)NB * BCAP * 4);
    int2* binned = (int2*)alloc((size_t)NB * BCAP * 8);
    unsigned short* xb  = (unsigned short*)alloc((size_t)N * FD * 2);
    unsigned short* hb1 = (unsigned short*)alloc((size_t)N * FD * 2);
    unsigned short* hb2 = (unsigned short*)alloc((size_t)N * FD * 2);
    unsigned short* Wp  = (unsigned short*)alloc((size_t)6 * FD * FD * 2);
    (void)ws_size; (void)n_in; (void)out_size;

    int n4 = N * FD / 4;
    int nCvt = (n4 + 255) / 256;
    prep_k<<<nCvt + 384 + 1, 256, 0, stream>>>(
        (const unsigned int*)d_in[1], flag, gcur, x, xb, n4,
        W1r, W1o, W2r, W2o, W3r, W3o, Wp, nCvt, E);
    bin_k<<<(E + 8191) / 8192, 512, 0, stream>>>(d_in[1], flag, gcur, binned, E);
    csr_k<<<NB, 256, 0, stream>>>(binned, gcur, rp, rend, srcs, N);

    const int stride = FD * FD;
    int gblocks = (N + 63) / 64;

    fused_k<1><<<gblocks, 256, 0, stream>>>(xb,  rp, rend, srcs, Wp + 0 * stride, Wp + 1 * stride, b1, hb1, N, 1);
    fused_k<1><<<gblocks, 256, 0, stream>>>(hb1, rp, rend, srcs, Wp + 2 * stride, Wp + 3 * stride, b2, hb2, N, 1);
    fused_k<0><<<gblocks, 256, 0, stream>>>(hb2, rp, rend, srcs, Wp + 4 * stride, Wp + 5 * stride, b3, d_out, N, 0);
}

// Round 6
// 196.603 us; speedup vs baseline: 1.0981x; 1.0981x over previous
//
#include <hip/hip_runtime.h>

#define FD 128
#define BCAP 8192
typedef __attribute__((ext_vector_type(8))) short short8;
typedef __attribute__((ext_vector_type(4))) float f32x4;

static __device__ __forceinline__ unsigned short f2b(float f) {
    unsigned u = __builtin_bit_cast(unsigned, f);
    unsigned r = (u + 0x7FFFu + ((u >> 16) & 1u)) >> 16;
    return (unsigned short)r;
}
static __device__ __forceinline__ float b2f(unsigned short h) {
    unsigned u = ((unsigned)h) << 16;
    return __builtin_bit_cast(float, u);
}

// edge accessors handling either int32 or int64 storage of (2,E) edge_index.
static __device__ __forceinline__ int edgeDst(const void* ei, int e, int E, int i32) {
    if (i32) return ((const int*)ei)[E + e];
    return ((const int*)ei)[2 * (E + e)];
}
static __device__ __forceinline__ int2 edgePair(const void* ei, int e, int E, int i32) {
    if (i32) { const int* p = (const int*)ei; return make_int2(p[e], p[E + e]); }
    const int* p = (const int*)ei;
    return make_int2(p[2 * e], p[2 * (E + e)]);
}

// ---------- prep: detect dtype + zero gcur | f32->bf16 cvt | weight repack ----------
__global__ __launch_bounds__(256) void prep_k(
        const unsigned int* __restrict__ ei, int* __restrict__ flag, int* __restrict__ gcur,
        const float* __restrict__ x, unsigned short* __restrict__ xb, int n4,
        const float* __restrict__ Wa, const float* __restrict__ Wb,
        const float* __restrict__ Wc, const float* __restrict__ Wd,
        const float* __restrict__ We, const float* __restrict__ Wf,
        unsigned short* __restrict__ P0, int nCvt, int E) {
    int b = blockIdx.x;
    int t = threadIdx.x;
    if (b < nCvt) {
        int i = b * 256 + t;
        if (i < n4) {
            float4 v = ((const float4*)x)[i];
            unsigned long long o = (unsigned long long)f2b(v.x)
                                 | ((unsigned long long)f2b(v.y) << 16)
                                 | ((unsigned long long)f2b(v.z) << 32)
                                 | ((unsigned long long)f2b(v.w) << 48);
            ((unsigned long long*)xb)[i] = o;
        }
    } else if (b < nCvt + 384) {
        int pb = b - nCvt;
        int which = pb >> 6;
        const float* W = which == 0 ? Wa : which == 1 ? Wb : which == 2 ? Wc
                       : which == 3 ? Wd : which == 4 ? We : Wf;
        unsigned short* P = P0 + (size_t)which * FD * FD;
        int i = (pb & 63) * 256 + t;
        int n = i >> 7, k = i & 127;
        P[(((k >> 3) * FD) + n) * 8 + (k & 7)] = f2b(W[n * FD + k]);
    } else {
        gcur[t] = 0;
        __shared__ int any;
        if (t == 0) any = 0;
        __syncthreads();
        int samples = 2048;
        if (samples > E) samples = E;
        for (int i = t; i < samples; i += 256)
            if (ei[2 * i + 1] != 0u) any = 1;
        __syncthreads();
        if (t == 0) *flag = any;   // any!=0 -> int32 data
    }
}

// ---------- bin edges into fixed-capacity bucket regions (bucket = dst>>8) ----------
__global__ __launch_bounds__(512) void bin_k(const void* __restrict__ ei,
                                             const int* __restrict__ flag,
                                             int* __restrict__ gcur,
                                             int2* __restrict__ binned, int E) {
    __shared__ int h[256];
    __shared__ int gb[256];
    __shared__ int lc[256];
    int t = threadIdx.x;
    if (t < 256) { h[t] = 0; lc[t] = 0; }
    __syncthreads();
    int i32 = *flag;
    int base = blockIdx.x * 8192;
#pragma unroll
    for (int i = 0; i < 16; ++i) {
        int e = base + i * 512 + t;
        if (e < E) atomicAdd(&h[edgeDst(ei, e, E, i32) >> 8], 1);
    }
    __syncthreads();
    if (t < 256 && h[t]) gb[t] = atomicAdd(&gcur[t], h[t]);
    __syncthreads();
#pragma unroll
    for (int i = 0; i < 16; ++i) {
        int e = base + i * 512 + t;
        if (e < E) {
            int2 p = edgePair(ei, e, E, i32);
            int bk = p.y >> 8;
            int r = atomicAdd(&lc[bk], 1);
            binned[(size_t)bk * BCAP + gb[bk] + r] = p;
        }
    }
}

// ---------- per-bucket CSR: rp/rend + srcs (bucketed layout, block-local writes) ----------
__global__ __launch_bounds__(256) void csr_k(const int2* __restrict__ binned,
                                             const int* __restrict__ gcur,
                                             int* __restrict__ rp, int* __restrict__ rend,
                                             int* __restrict__ srcs, int N) {
    __shared__ int h[256];
    __shared__ int cur[256];
    int t = threadIdx.x;
    int b = blockIdx.x;
    int base = b * BCAP;
    int cnt = gcur[b];
    int n0 = b << 8;
    h[t] = 0;
    __syncthreads();
    for (int i = t; i < cnt; i += 256)
        atomicAdd(&h[binned[base + i].y - n0], 1);
    __syncthreads();
    int v = h[t];
    for (int off = 1; off < 256; off <<= 1) {
        int add = (t >= off) ? h[t - off] : 0;
        __syncthreads();
        h[t] += add;
        __syncthreads();
    }
    int excl = h[t] - v;
    int n = n0 + t;
    if (n < N) { rp[n] = base + excl; rend[n] = base + excl + v; }
    cur[t] = base + excl;
    __syncthreads();
    for (int i = t; i < cnt; i += 256) {
        int2 p = binned[base + i];
        int pos = atomicAdd(&cur[p.y - n0], 1);
        srcs[pos] = p.x;
    }
}

// ---------- aggregation: one wave per node, dwordx4 gathers, 4 loads in flight ----------
__global__ __launch_bounds__(256) void aggb_k(const unsigned short* __restrict__ hb,
                                              const int* __restrict__ rp,
                                              const int* __restrict__ rend,
                                              const int* __restrict__ srcs,
                                              unsigned short* __restrict__ aggb, int N) {
    int wid = threadIdx.x >> 6, lane = threadIdx.x & 63;
    int node = blockIdx.x * 4 + wid;
    if (node >= N) return;
    int g = lane >> 4, c = lane & 15;
    const unsigned short* hbc = hb + c * 8;
    int idx = rp[node] + g;
    int e1 = rend[node];
    float a[8];
#pragma unroll
    for (int j = 0; j < 8; ++j) a[j] = 0.f;

#define ACC8(v)                                                        \
    a[0] += b2f((unsigned short)(v.x & 0xFFFF));                       \
    a[1] += b2f((unsigned short)(v.x >> 16));                          \
    a[2] += b2f((unsigned short)(v.y & 0xFFFF));                       \
    a[3] += b2f((unsigned short)(v.y >> 16));                          \
    a[4] += b2f((unsigned short)(v.z & 0xFFFF));                       \
    a[5] += b2f((unsigned short)(v.z >> 16));                          \
    a[6] += b2f((unsigned short)(v.w & 0xFFFF));                       \
    a[7] += b2f((unsigned short)(v.w >> 16));

    for (; idx + 12 < e1; idx += 16) {
        int s0 = srcs[idx];
        int s1 = srcs[idx + 4];
        int s2 = srcs[idx + 8];
        int s3 = srcs[idx + 12];
        uint4 v0 = *(const uint4*)(hbc + (size_t)s0 * FD);
        uint4 v1 = *(const uint4*)(hbc + (size_t)s1 * FD);
        uint4 v2 = *(const uint4*)(hbc + (size_t)s2 * FD);
        uint4 v3 = *(const uint4*)(hbc + (size_t)s3 * FD);
        ACC8(v0) ACC8(v1) ACC8(v2) ACC8(v3)
    }
    for (; idx < e1; idx += 4) {
        int s0 = srcs[idx];
        uint4 v0 = *(const uint4*)(hbc + (size_t)s0 * FD);
        ACC8(v0)
    }
#undef ACC8

#pragma unroll
    for (int j = 0; j < 8; ++j) {
        a[j] += __shfl_xor(a[j], 16);
        a[j] += __shfl_xor(a[j], 32);
    }
    if (lane < 16) {
        uint4 o;
        o.x = (unsigned)f2b(a[0]) | ((unsigned)f2b(a[1]) << 16);
        o.y = (unsigned)f2b(a[2]) | ((unsigned)f2b(a[3]) << 16);
        o.z = (unsigned)f2b(a[4]) | ((unsigned)f2b(a[5]) << 16);
        o.w = (unsigned)f2b(a[6]) | ((unsigned)f2b(a[7]) << 16);
        *(uint4*)(aggb + (size_t)node * FD + c * 8) = o;
    }
}

// ---------- MFMA GEMM: out = [agg|hin] @ [Wrel;Wroot]^T + b ----------
template <int OUT_BF16>
__global__ __launch_bounds__(256) void mgemm_k(
        const unsigned short* __restrict__ aggb, const unsigned short* __restrict__ hin,
        const unsigned short* __restrict__ BpRel, const unsigned short* __restrict__ BpRoot,
        const float* __restrict__ bias, void* __restrict__ outp, int N, int relu) {
    int wid = threadIdx.x >> 6, lane = threadIdx.x & 63;
    int l15 = lane & 15, lhi = lane >> 4;
    int b0 = blockIdx.x * 64;
    int n0 = wid * 32;

    f32x4 acc[4][2];
#pragma unroll
    for (int r = 0; r < 4; ++r)
#pragma unroll
        for (int t = 0; t < 2; ++t) acc[r][t] = (f32x4){0.f, 0.f, 0.f, 0.f};

#pragma unroll
    for (int half = 0; half < 2; ++half) {
        const unsigned short* F  = half ? hin : aggb;
        const unsigned short* Bp = half ? BpRoot : BpRel;
#pragma unroll
        for (int kk = 0; kk < 4; ++kk) {
            short8 bf0 = *(const short8*)(Bp + (((kk * 4 + lhi) * FD) + n0 + l15) * 8);
            short8 bf1 = *(const short8*)(Bp + (((kk * 4 + lhi) * FD) + n0 + 16 + l15) * 8);
#pragma unroll
            for (int r = 0; r < 4; ++r) {
                int row = b0 + r * 16 + l15;
                if (row >= N) row = N - 1;
                short8 af = *(const short8*)(F + (size_t)row * FD + kk * 32 + lhi * 8);
                acc[r][0] = __builtin_amdgcn_mfma_f32_16x16x32_bf16(af, bf0, acc[r][0], 0, 0, 0);
                acc[r][1] = __builtin_amdgcn_mfma_f32_16x16x32_bf16(af, bf1, acc[r][1], 0, 0, 0);
            }
        }
    }

    float bb0 = bias[n0 + l15];
    float bb1 = bias[n0 + 16 + l15];
#pragma unroll
    for (int r = 0; r < 4; ++r) {
#pragma unroll
        for (int t = 0; t < 2; ++t) {
            int col = n0 + t * 16 + l15;
            float bb = t ? bb1 : bb0;
#pragma unroll
            for (int j = 0; j < 4; ++j) {
                int row = b0 + r * 16 + lhi * 4 + j;
                if (row < N) {
                    float v = acc[r][t][j] + bb;
                    if (relu) v = fmaxf(v, 0.f);
                    if (OUT_BF16)
                        ((unsigned short*)outp)[(size_t)row * FD + col] = f2b(v);
                    else
                        ((float*)outp)[(size_t)row * FD + col] = v;
                }
            }
        }
    }
}

extern "C" void kernel_launch(void* const* d_in, const int* in_sizes, int n_in,
                              void* d_out, int out_size, void* d_ws, size_t ws_size,
                              hipStream_t stream) {
    const float* x   = (const float*)d_in[0];
    const float* W1r = (const float*)d_in[2];
    const float* b1  = (const float*)d_in[3];
    const float* W1o = (const float*)d_in[4];
    const float* W2r = (const float*)d_in[5];
    const float* b2  = (const float*)d_in[6];
    const float* W2o = (const float*)d_in[7];
    const float* W3r = (const float*)d_in[8];
    const float* b3  = (const float*)d_in[9];
    const float* W3o = (const float*)d_in[10];

    int N = in_sizes[0] / FD;
    int E = in_sizes[1] / 2;
    int NB = (N + 255) >> 8;   // buckets of 256 nodes

    char* ws = (char*)d_ws;
    size_t off = 0;
    auto alloc = [&](size_t bytes) -> void* {
        void* p = ws + off;
        off = (off + bytes + 255) & ~(size_t)255;
        return p;
    };
    int*  flag   = (int*)alloc(4);
    int*  gcur   = (int*)alloc(256 * 4);
    int*  rp     = (int*)alloc((size_t)N * 4);
    int*  rend   = (int*)alloc((size_t)N * 4);
    int*  srcs   = (int*)alloc((size_t)NB * BCAP * 4);
    int2* binned = (int2*)alloc((size_t)NB * BCAP * 8);
    unsigned short* xb   = (unsigned short*)alloc((size_t)N * FD * 2);
    unsigned short* hb1  = (unsigned short*)alloc((size_t)N * FD * 2);
    unsigned short* hb2  = (unsigned short*)alloc((size_t)N * FD * 2);
    unsigned short* aggb = (unsigned short*)alloc((size_t)N * FD * 2);
    unsigned short* Wp   = (unsigned short*)alloc((size_t)6 * FD * FD * 2);
    (void)ws_size; (void)n_in; (void)out_size;

    int n4 = N * FD / 4;
    int nCvt = (n4 + 255) / 256;
    prep_k<<<nCvt + 384 + 1, 256, 0, stream>>>(
        (const unsigned int*)d_in[1], flag, gcur, x, xb, n4,
        W1r, W1o, W2r, W2o, W3r, W3o, Wp, nCvt, E);
    bin_k<<<(E + 8191) / 8192, 512, 0, stream>>>(d_in[1], flag, gcur, binned, E);
    csr_k<<<NB, 256, 0, stream>>>(binned, gcur, rp, rend, srcs, N);

    const int stride = FD * FD;
    int ablocks = (N + 3) / 4;
    int gblocks = (N + 63) / 64;

    aggb_k<<<ablocks, 256, 0, stream>>>(xb, rp, rend, srcs, aggb, N);
    mgemm_k<1><<<gblocks, 256, 0, stream>>>(aggb, xb, Wp + 0 * stride, Wp + 1 * stride, b1, hb1, N, 1);

    aggb_k<<<ablocks, 256, 0, stream>>>(hb1, rp, rend, srcs, aggb, N);
    mgemm_k<1><<<gblocks, 256, 0, stream>>>(aggb, hb1, Wp + 2 * stride, Wp + 3 * stride, b2, hb2, N, 1);

    aggb_k<<<ablocks, 256, 0, stream>>>(hb2, rp, rend, srcs, aggb, N);
    mgemm_k<0><<<gblocks, 256, 0, stream>>>(aggb, hb2, Wp + 4 * stride, Wp + 5 * stride, b3, d_out, N, 0);
}

// Round 7
// 191.457 us; speedup vs baseline: 1.1277x; 1.0269x over previous
//
#include <hip/hip_runtime.h>

#define FD 128
#define BCAP 8192
typedef __attribute__((ext_vector_type(8))) short short8;
typedef __attribute__((ext_vector_type(4))) float f32x4;

static __device__ __forceinline__ unsigned short f2b(float f) {
    unsigned u = __builtin_bit_cast(unsigned, f);
    unsigned r = (u + 0x7FFFu + ((u >> 16) & 1u)) >> 16;
    return (unsigned short)r;
}
static __device__ __forceinline__ float b2f(unsigned short h) {
    unsigned u = ((unsigned)h) << 16;
    return __builtin_bit_cast(float, u);
}

// edge accessors handling either int32 or int64 storage of (2,E) edge_index.
static __device__ __forceinline__ int2 edgePair(const void* ei, int e, int E, int i32) {
    if (i32) { const int* p = (const int*)ei; return make_int2(p[e], p[E + e]); }
    const int* p = (const int*)ei;
    return make_int2(p[2 * e], p[2 * (E + e)]);
}

// ---------- prep: detect dtype + zero gcur | f32->bf16 cvt | weight repack ----------
__global__ __launch_bounds__(256) void prep_k(
        const unsigned int* __restrict__ ei, int* __restrict__ flag, int* __restrict__ gcur,
        const float* __restrict__ x, unsigned short* __restrict__ xb, int n4,
        const float* __restrict__ Wa, const float* __restrict__ Wb,
        const float* __restrict__ Wc, const float* __restrict__ Wd,
        const float* __restrict__ We, const float* __restrict__ Wf,
        unsigned short* __restrict__ P0, int nCvt, int E) {
    int b = blockIdx.x;
    int t = threadIdx.x;
    if (b < nCvt) {
        int i = b * 256 + t;
        if (i < n4) {
            float4 v = ((const float4*)x)[i];
            unsigned long long o = (unsigned long long)f2b(v.x)
                                 | ((unsigned long long)f2b(v.y) << 16)
                                 | ((unsigned long long)f2b(v.z) << 32)
                                 | ((unsigned long long)f2b(v.w) << 48);
            ((unsigned long long*)xb)[i] = o;
        }
    } else if (b < nCvt + 384) {
        int pb = b - nCvt;
        int which = pb >> 6;
        const float* W = which == 0 ? Wa : which == 1 ? Wb : which == 2 ? Wc
                       : which == 3 ? Wd : which == 4 ? We : Wf;
        unsigned short* P = P0 + (size_t)which * FD * FD;
        int i = (pb & 63) * 256 + t;
        int n = i >> 7, k = i & 127;
        P[(((k >> 3) * FD) + n) * 8 + (k & 7)] = f2b(W[n * FD + k]);
    } else {
        gcur[t] = 0;
        __shared__ int any;
        if (t == 0) any = 0;
        __syncthreads();
        int samples = 2048;
        if (samples > E) samples = E;
        for (int i = t; i < samples; i += 256)
            if (ei[2 * i + 1] != 0u) any = 1;
        __syncthreads();
        if (t == 0) *flag = any;   // any!=0 -> int32 data
    }
}

// ---------- bin edges into fixed-capacity bucket regions (bucket = dst>>8) ----------
// Edge pairs cached in registers across the histogram and scatter passes.
__global__ __launch_bounds__(512) void bin_k(const void* __restrict__ ei,
                                             const int* __restrict__ flag,
                                             int* __restrict__ gcur,
                                             int2* __restrict__ binned, int E) {
    __shared__ int h[256];
    __shared__ int gb[256];
    __shared__ int lc[256];
    int t = threadIdx.x;
    if (t < 256) { h[t] = 0; lc[t] = 0; }
    __syncthreads();
    int i32 = *flag;
    int base = blockIdx.x * 8192;
    int2 pr[16];
#pragma unroll
    for (int i = 0; i < 16; ++i) {
        int e = base + i * 512 + t;
        if (e < E) {
            pr[i] = edgePair(ei, e, E, i32);
            atomicAdd(&h[pr[i].y >> 8], 1);
        } else {
            pr[i] = make_int2(-1, -1);
        }
    }
    __syncthreads();
    if (t < 256 && h[t]) gb[t] = atomicAdd(&gcur[t], h[t]);
    __syncthreads();
#pragma unroll
    for (int i = 0; i < 16; ++i) {
        if (pr[i].y >= 0) {
            int bk = pr[i].y >> 8;
            int r = atomicAdd(&lc[bk], 1);
            binned[(size_t)bk * BCAP + gb[bk] + r] = pr[i];
        }
    }
}

// ---------- per-bucket CSR: rpe(start,end) + srcs (bucketed, block-local writes) ----------
__global__ __launch_bounds__(256) void csr_k(const int2* __restrict__ binned,
                                             const int* __restrict__ gcur,
                                             int2* __restrict__ rpe,
                                             int* __restrict__ srcs, int N) {
    __shared__ int h[256];
    __shared__ int cur[256];
    int t = threadIdx.x;
    int b = blockIdx.x;
    int base = b * BCAP;
    int cnt = gcur[b];
    int n0 = b << 8;
    h[t] = 0;
    __syncthreads();
    for (int i = t; i < cnt; i += 256)
        atomicAdd(&h[binned[base + i].y - n0], 1);
    __syncthreads();
    int v = h[t];
    for (int off = 1; off < 256; off <<= 1) {
        int add = (t >= off) ? h[t - off] : 0;
        __syncthreads();
        h[t] += add;
        __syncthreads();
    }
    int excl = h[t] - v;
    int n = n0 + t;
    if (n < N) rpe[n] = make_int2(base + excl, base + excl + v);
    cur[t] = base + excl;
    __syncthreads();
    for (int i = t; i < cnt; i += 256) {
        int2 p = binned[base + i];
        int pos = atomicAdd(&cur[p.y - n0], 1);
        srcs[pos] = p.x;
    }
}

// ---------- aggregation: one wave per node, dwordx4 gathers, 4 loads in flight ----------
__global__ __launch_bounds__(256) void aggb_k(const unsigned short* __restrict__ hb,
                                              const int2* __restrict__ rpe,
                                              const int* __restrict__ srcs,
                                              unsigned short* __restrict__ aggb, int N) {
    int wid = threadIdx.x >> 6, lane = threadIdx.x & 63;
    int node = blockIdx.x * 4 + wid;
    if (node >= N) return;
    int g = lane >> 4, c = lane & 15;
    const unsigned short* hbc = hb + c * 8;
    int2 se = rpe[node];
    int idx = se.x + g;
    int e1 = se.y;
    float a[8];
#pragma unroll
    for (int j = 0; j < 8; ++j) a[j] = 0.f;

#define ACC8(v)                                                        \
    a[0] += b2f((unsigned short)(v.x & 0xFFFF));                       \
    a[1] += b2f((unsigned short)(v.x >> 16));                          \
    a[2] += b2f((unsigned short)(v.y & 0xFFFF));                       \
    a[3] += b2f((unsigned short)(v.y >> 16));                          \
    a[4] += b2f((unsigned short)(v.z & 0xFFFF));                       \
    a[5] += b2f((unsigned short)(v.z >> 16));                          \
    a[6] += b2f((unsigned short)(v.w & 0xFFFF));                       \
    a[7] += b2f((unsigned short)(v.w >> 16));

    for (; idx + 12 < e1; idx += 16) {
        int s0 = srcs[idx];
        int s1 = srcs[idx + 4];
        int s2 = srcs[idx + 8];
        int s3 = srcs[idx + 12];
        uint4 v0 = *(const uint4*)(hbc + (size_t)s0 * FD);
        uint4 v1 = *(const uint4*)(hbc + (size_t)s1 * FD);
        uint4 v2 = *(const uint4*)(hbc + (size_t)s2 * FD);
        uint4 v3 = *(const uint4*)(hbc + (size_t)s3 * FD);
        ACC8(v0) ACC8(v1) ACC8(v2) ACC8(v3)
    }
    for (; idx < e1; idx += 4) {
        int s0 = srcs[idx];
        uint4 v0 = *(const uint4*)(hbc + (size_t)s0 * FD);
        ACC8(v0)
    }
#undef ACC8

#pragma unroll
    for (int j = 0; j < 8; ++j) {
        a[j] += __shfl_xor(a[j], 16);
        a[j] += __shfl_xor(a[j], 32);
    }
    if (lane < 16) {
        uint4 o;
        o.x = (unsigned)f2b(a[0]) | ((unsigned)f2b(a[1]) << 16);
        o.y = (unsigned)f2b(a[2]) | ((unsigned)f2b(a[3]) << 16);
        o.z = (unsigned)f2b(a[4]) | ((unsigned)f2b(a[5]) << 16);
        o.w = (unsigned)f2b(a[6]) | ((unsigned)f2b(a[7]) << 16);
        *(uint4*)(aggb + (size_t)node * FD + c * 8) = o;
    }
}

// ---------- MFMA GEMM: out = [agg|hin] @ [Wrel;Wroot]^T + b ----------
template <int OUT_BF16>
__global__ __launch_bounds__(256) void mgemm_k(
        const unsigned short* __restrict__ aggb, const unsigned short* __restrict__ hin,
        const unsigned short* __restrict__ BpRel, const unsigned short* __restrict__ BpRoot,
        const float* __restrict__ bias, void* __restrict__ outp, int N, int relu) {
    int wid = threadIdx.x >> 6, lane = threadIdx.x & 63;
    int l15 = lane & 15, lhi = lane >> 4;
    int b0 = blockIdx.x * 64;
    int n0 = wid * 32;

    f32x4 acc[4][2];
#pragma unroll
    for (int r = 0; r < 4; ++r)
#pragma unroll
        for (int t = 0; t < 2; ++t) acc[r][t] = (f32x4){0.f, 0.f, 0.f, 0.f};

#pragma unroll
    for (int half = 0; half < 2; ++half) {
        const unsigned short* F  = half ? hin : aggb;
        const unsigned short* Bp = half ? BpRoot : BpRel;
#pragma unroll
        for (int kk = 0; kk < 4; ++kk) {
            short8 bf0 = *(const short8*)(Bp + (((kk * 4 + lhi) * FD) + n0 + l15) * 8);
            short8 bf1 = *(const short8*)(Bp + (((kk * 4 + lhi) * FD) + n0 + 16 + l15) * 8);
#pragma unroll
            for (int r = 0; r < 4; ++r) {
                int row = b0 + r * 16 + l15;
                if (row >= N) row = N - 1;
                short8 af = *(const short8*)(F + (size_t)row * FD + kk * 32 + lhi * 8);
                acc[r][0] = __builtin_amdgcn_mfma_f32_16x16x32_bf16(af, bf0, acc[r][0], 0, 0, 0);
                acc[r][1] = __builtin_amdgcn_mfma_f32_16x16x32_bf16(af, bf1, acc[r][1], 0, 0, 0);
            }
        }
    }

    float bb0 = bias[n0 + l15];
    float bb1 = bias[n0 + 16 + l15];
#pragma unroll
    for (int r = 0; r < 4; ++r) {
#pragma unroll
        for (int t = 0; t < 2; ++t) {
            int col = n0 + t * 16 + l15;
            float bb = t ? bb1 : bb0;
#pragma unroll
            for (int j = 0; j < 4; ++j) {
                int row = b0 + r * 16 + lhi * 4 + j;
                if (row < N) {
                    float v = acc[r][t][j] + bb;
                    if (relu) v = fmaxf(v, 0.f);
                    if (OUT_BF16)
                        ((unsigned short*)outp)[(size_t)row * FD + col] = f2b(v);
                    else
                        __builtin_nontemporal_store(v, &((float*)outp)[(size_t)row * FD + col]);
                }
            }
        }
    }
}

extern "C" void kernel_launch(void* const* d_in, const int* in_sizes, int n_in,
                              void* d_out, int out_size, void* d_ws, size_t ws_size,
                              hipStream_t stream) {
    const float* x   = (const float*)d_in[0];
    const float* W1r = (const float*)d_in[2];
    const float* b1  = (const float*)d_in[3];
    const float* W1o = (const float*)d_in[4];
    const float* W2r = (const float*)d_in[5];
    const float* b2  = (const float*)d_in[6];
    const float* W2o = (const float*)d_in[7];
    const float* W3r = (const float*)d_in[8];
    const float* b3  = (const float*)d_in[9];
    const float* W3o = (const float*)d_in[10];

    int N = in_sizes[0] / FD;
    int E = in_sizes[1] / 2;
    int NB = (N + 255) >> 8;   // buckets of 256 nodes

    char* ws = (char*)d_ws;
    size_t off = 0;
    auto alloc = [&](size_t bytes) -> void* {
        void* p = ws + off;
        off = (off + bytes + 255) & ~(size_t)255;
        return p;
    };
    int*  flag   = (int*)alloc(4);
    int*  gcur   = (int*)alloc(256 * 4);
    int2* rpe    = (int2*)alloc((size_t)N * 8);
    int*  srcs   = (int*)alloc((size_t)NB * BCAP * 4);
    int2* binned = (int2*)alloc((size_t)NB * BCAP * 8);
    unsigned short* xb   = (unsigned short*)alloc((size_t)N * FD * 2);
    unsigned short* hb1  = (unsigned short*)alloc((size_t)N * FD * 2);
    unsigned short* hb2  = (unsigned short*)alloc((size_t)N * FD * 2);
    unsigned short* aggb = (unsigned short*)alloc((size_t)N * FD * 2);
    unsigned short* Wp   = (unsigned short*)alloc((size_t)6 * FD * FD * 2);
    (void)ws_size; (void)n_in; (void)out_size;

    int n4 = N * FD / 4;
    int nCvt = (n4 + 255) / 256;
    prep_k<<<nCvt + 384 + 1, 256, 0, stream>>>(
        (const unsigned int*)d_in[1], flag, gcur, x, xb, n4,
        W1r, W1o, W2r, W2o, W3r, W3o, Wp, nCvt, E);
    bin_k<<<(E + 8191) / 8192, 512, 0, stream>>>(d_in[1], flag, gcur, binned, E);
    csr_k<<<NB, 256, 0, stream>>>(binned, gcur, rpe, srcs, N);

    const int stride = FD * FD;
    int ablocks = (N + 3) / 4;
    int gblocks = (N + 63) / 64;

    aggb_k<<<ablocks, 256, 0, stream>>>(xb, rpe, srcs, aggb, N);
    mgemm_k<1><<<gblocks, 256, 0, stream>>>(aggb, xb, Wp + 0 * stride, Wp + 1 * stride, b1, hb1, N, 1);

    aggb_k<<<ablocks, 256, 0, stream>>>(hb1, rpe, srcs, aggb, N);
    mgemm_k<1><<<gblocks, 256, 0, stream>>>(aggb, hb1, Wp + 2 * stride, Wp + 3 * stride, b2, hb2, N, 1);

    aggb_k<<<ablocks, 256, 0, stream>>>(hb2, rpe, srcs, aggb, N);
    mgemm_k<0><<<gblocks, 256, 0, stream>>>(aggb, hb2, Wp + 4 * stride, Wp + 5 * stride, b3, d_out, N, 0);
}

// Round 8
// 190.308 us; speedup vs baseline: 1.1345x; 1.0060x over previous
//
#include <hip/hip_runtime.h>

#define FD 128
#define BCAP 8192
typedef __attribute__((ext_vector_type(8))) short short8;
typedef __attribute__((ext_vector_type(4))) float f32x4;

static __device__ __forceinline__ unsigned short f2b(float f) {
    unsigned u = __builtin_bit_cast(unsigned, f);
    unsigned r = (u + 0x7FFFu + ((u >> 16) & 1u)) >> 16;
    return (unsigned short)r;
}
static __device__ __forceinline__ float b2f(unsigned short h) {
    unsigned u = ((unsigned)h) << 16;
    return __builtin_bit_cast(float, u);
}

// edge accessors handling either int32 or int64 storage of (2,E) edge_index.
static __device__ __forceinline__ int2 edgePair(const void* ei, int e, int E, int i32) {
    if (i32) { const int* p = (const int*)ei; return make_int2(p[e], p[E + e]); }
    const int* p = (const int*)ei;
    return make_int2(p[2 * e], p[2 * (E + e)]);
}

// ---------- prep: detect dtype + zero gcur | f32->bf16 cvt | weight repack ----------
__global__ __launch_bounds__(256) void prep_k(
        const unsigned int* __restrict__ ei, int* __restrict__ flag, int* __restrict__ gcur,
        const float* __restrict__ x, unsigned short* __restrict__ xb, int n4,
        const float* __restrict__ Wa, const float* __restrict__ Wb,
        const float* __restrict__ Wc, const float* __restrict__ Wd,
        const float* __restrict__ We, const float* __restrict__ Wf,
        unsigned short* __restrict__ P0, int nCvt, int E) {
    int b = blockIdx.x;
    int t = threadIdx.x;
    if (b < nCvt) {
        int i = b * 256 + t;
        if (i < n4) {
            float4 v = ((const float4*)x)[i];
            unsigned long long o = (unsigned long long)f2b(v.x)
                                 | ((unsigned long long)f2b(v.y) << 16)
                                 | ((unsigned long long)f2b(v.z) << 32)
                                 | ((unsigned long long)f2b(v.w) << 48);
            ((unsigned long long*)xb)[i] = o;
        }
    } else if (b < nCvt + 384) {
        int pb = b - nCvt;
        int which = pb >> 6;
        const float* W = which == 0 ? Wa : which == 1 ? Wb : which == 2 ? Wc
                       : which == 3 ? Wd : which == 4 ? We : Wf;
        unsigned short* P = P0 + (size_t)which * FD * FD;
        int i = (pb & 63) * 256 + t;
        int n = i >> 7, k = i & 127;
        P[(((k >> 3) * FD) + n) * 8 + (k & 7)] = f2b(W[n * FD + k]);
    } else {
        gcur[t] = 0;
        __shared__ int any;
        if (t == 0) any = 0;
        __syncthreads();
        int samples = 2048;
        if (samples > E) samples = E;
        for (int i = t; i < samples; i += 256)
            if (ei[2 * i + 1] != 0u) any = 1;
        __syncthreads();
        if (t == 0) *flag = any;   // any!=0 -> int32 data
    }
}

// ---------- bin edges into fixed-capacity bucket regions (bucket = dst>>8) ----------
__global__ __launch_bounds__(512) void bin_k(const void* __restrict__ ei,
                                             const int* __restrict__ flag,
                                             int* __restrict__ gcur,
                                             int2* __restrict__ binned, int E) {
    __shared__ int h[256];
    __shared__ int gb[256];
    __shared__ int lc[256];
    int t = threadIdx.x;
    if (t < 256) { h[t] = 0; lc[t] = 0; }
    __syncthreads();
    int i32 = *flag;
    int base = blockIdx.x * 8192;
    int2 pr[16];
#pragma unroll
    for (int i = 0; i < 16; ++i) {
        int e = base + i * 512 + t;
        if (e < E) {
            pr[i] = edgePair(ei, e, E, i32);
            atomicAdd(&h[pr[i].y >> 8], 1);
        } else {
            pr[i] = make_int2(-1, -1);
        }
    }
    __syncthreads();
    if (t < 256 && h[t]) gb[t] = atomicAdd(&gcur[t], h[t]);
    __syncthreads();
#pragma unroll
    for (int i = 0; i < 16; ++i) {
        if (pr[i].y >= 0) {
            int bk = pr[i].y >> 8;
            int r = atomicAdd(&lc[bk], 1);
            binned[(size_t)bk * BCAP + gb[bk] + r] = pr[i];
        }
    }
}

// ---------- per-bucket CSR: rpe(start,end) + srcs (bucketed, block-local writes) ----------
__global__ __launch_bounds__(256) void csr_k(const int2* __restrict__ binned,
                                             const int* __restrict__ gcur,
                                             int2* __restrict__ rpe,
                                             int* __restrict__ srcs, int N) {
    __shared__ int h[256];
    __shared__ int cur[256];
    int t = threadIdx.x;
    int b = blockIdx.x;
    int base = b * BCAP;
    int cnt = gcur[b];
    int n0 = b << 8;
    h[t] = 0;
    __syncthreads();
    for (int i = t; i < cnt; i += 256)
        atomicAdd(&h[binned[base + i].y - n0], 1);
    __syncthreads();
    int v = h[t];
    for (int off = 1; off < 256; off <<= 1) {
        int add = (t >= off) ? h[t - off] : 0;
        __syncthreads();
        h[t] += add;
        __syncthreads();
    }
    int excl = h[t] - v;
    int n = n0 + t;
    if (n < N) rpe[n] = make_int2(base + excl, base + excl + v);
    cur[t] = base + excl;
    __syncthreads();
    for (int i = t; i < cnt; i += 256) {
        int2 p = binned[base + i];
        int pos = atomicAdd(&cur[p.y - n0], 1);
        srcs[pos] = p.x;
    }
}

// ---------- aggregation: one wave per node, dwordx4 gathers, 4 loads in flight ----------
__global__ __launch_bounds__(256) void aggb_k(const unsigned short* __restrict__ hb,
                                              const int2* __restrict__ rpe,
                                              const int* __restrict__ srcs,
                                              unsigned short* __restrict__ aggb, int N) {
    int wid = threadIdx.x >> 6, lane = threadIdx.x & 63;
    int node = blockIdx.x * 4 + wid;
    if (node >= N) return;
    int g = lane >> 4, c = lane & 15;
    const unsigned short* hbc = hb + c * 8;
    int2 se = rpe[node];
    int idx = se.x + g;
    int e1 = se.y;
    float a[8];
#pragma unroll
    for (int j = 0; j < 8; ++j) a[j] = 0.f;

#define ACC8(v)                                                        \
    a[0] += b2f((unsigned short)(v.x & 0xFFFF));                       \
    a[1] += b2f((unsigned short)(v.x >> 16));                          \
    a[2] += b2f((unsigned short)(v.y & 0xFFFF));                       \
    a[3] += b2f((unsigned short)(v.y >> 16));                          \
    a[4] += b2f((unsigned short)(v.z & 0xFFFF));                       \
    a[5] += b2f((unsigned short)(v.z >> 16));                          \
    a[6] += b2f((unsigned short)(v.w & 0xFFFF));                       \
    a[7] += b2f((unsigned short)(v.w >> 16));

    for (; idx + 12 < e1; idx += 16) {
        int s0 = srcs[idx];
        int s1 = srcs[idx + 4];
        int s2 = srcs[idx + 8];
        int s3 = srcs[idx + 12];
        uint4 v0 = *(const uint4*)(hbc + (size_t)s0 * FD);
        uint4 v1 = *(const uint4*)(hbc + (size_t)s1 * FD);
        uint4 v2 = *(const uint4*)(hbc + (size_t)s2 * FD);
        uint4 v3 = *(const uint4*)(hbc + (size_t)s3 * FD);
        ACC8(v0) ACC8(v1) ACC8(v2) ACC8(v3)
    }
    for (; idx < e1; idx += 4) {
        int s0 = srcs[idx];
        uint4 v0 = *(const uint4*)(hbc + (size_t)s0 * FD);
        ACC8(v0)
    }
#undef ACC8

#pragma unroll
    for (int j = 0; j < 8; ++j) {
        a[j] += __shfl_xor(a[j], 16);
        a[j] += __shfl_xor(a[j], 32);
    }
    if (lane < 16) {
        uint4 o;
        o.x = (unsigned)f2b(a[0]) | ((unsigned)f2b(a[1]) << 16);
        o.y = (unsigned)f2b(a[2]) | ((unsigned)f2b(a[3]) << 16);
        o.z = (unsigned)f2b(a[4]) | ((unsigned)f2b(a[5]) << 16);
        o.w = (unsigned)f2b(a[6]) | ((unsigned)f2b(a[7]) << 16);
        *(uint4*)(aggb + (size_t)node * FD + c * 8) = o;
    }
}

// ---------- MFMA GEMM: out = [agg|hin] @ [Wrel;Wroot]^T + b ----------
// 32-node tile (was 64): doubles grid to ~6 blocks/CU for latency hiding.
template <int OUT_BF16>
__global__ __launch_bounds__(256) void mgemm_k(
        const unsigned short* __restrict__ aggb, const unsigned short* __restrict__ hin,
        const unsigned short* __restrict__ BpRel, const unsigned short* __restrict__ BpRoot,
        const float* __restrict__ bias, void* __restrict__ outp, int N, int relu) {
    int wid = threadIdx.x >> 6, lane = threadIdx.x & 63;
    int l15 = lane & 15, lhi = lane >> 4;
    int b0 = blockIdx.x * 32;
    int n0 = wid * 32;

    f32x4 acc[2][2];
#pragma unroll
    for (int r = 0; r < 2; ++r)
#pragma unroll
        for (int t = 0; t < 2; ++t) acc[r][t] = (f32x4){0.f, 0.f, 0.f, 0.f};

#pragma unroll
    for (int half = 0; half < 2; ++half) {
        const unsigned short* F  = half ? hin : aggb;
        const unsigned short* Bp = half ? BpRoot : BpRel;
#pragma unroll
        for (int kk = 0; kk < 4; ++kk) {
            short8 bf0 = *(const short8*)(Bp + (((kk * 4 + lhi) * FD) + n0 + l15) * 8);
            short8 bf1 = *(const short8*)(Bp + (((kk * 4 + lhi) * FD) + n0 + 16 + l15) * 8);
#pragma unroll
            for (int r = 0; r < 2; ++r) {
                int row = b0 + r * 16 + l15;
                if (row >= N) row = N - 1;
                short8 af = *(const short8*)(F + (size_t)row * FD + kk * 32 + lhi * 8);
                acc[r][0] = __builtin_amdgcn_mfma_f32_16x16x32_bf16(af, bf0, acc[r][0], 0, 0, 0);
                acc[r][1] = __builtin_amdgcn_mfma_f32_16x16x32_bf16(af, bf1, acc[r][1], 0, 0, 0);
            }
        }
    }

    float bb0 = bias[n0 + l15];
    float bb1 = bias[n0 + 16 + l15];
#pragma unroll
    for (int r = 0; r < 2; ++r) {
#pragma unroll
        for (int t = 0; t < 2; ++t) {
            int col = n0 + t * 16 + l15;
            float bb = t ? bb1 : bb0;
#pragma unroll
            for (int j = 0; j < 4; ++j) {
                int row = b0 + r * 16 + lhi * 4 + j;
                if (row < N) {
                    float v = acc[r][t][j] + bb;
                    if (relu) v = fmaxf(v, 0.f);
                    if (OUT_BF16)
                        ((unsigned short*)outp)[(size_t)row * FD + col] = f2b(v);
                    else
                        __builtin_nontemporal_store(v, &((float*)outp)[(size_t)row * FD + col]);
                }
            }
        }
    }
}

extern "C" void kernel_launch(void* const* d_in, const int* in_sizes, int n_in,
                              void* d_out, int out_size, void* d_ws, size_t ws_size,
                              hipStream_t stream) {
    const float* x   = (const float*)d_in[0];
    const float* W1r = (const float*)d_in[2];
    const float* b1  = (const float*)d_in[3];
    const float* W1o = (const float*)d_in[4];
    const float* W2r = (const float*)d_in[5];
    const float* b2  = (const float*)d_in[6];
    const float* W2o = (const float*)d_in[7];
    const float* W3r = (const float*)d_in[8];
    const float* b3  = (const float*)d_in[9];
    const float* W3o = (const float*)d_in[10];

    int N = in_sizes[0] / FD;
    int E = in_sizes[1] / 2;
    int NB = (N + 255) >> 8;   // buckets of 256 nodes

    char* ws = (char*)d_ws;
    size_t off = 0;
    auto alloc = [&](size_t bytes) -> void* {
        void* p = ws + off;
        off = (off + bytes + 255) & ~(size_t)255;
        return p;
    };
    int*  flag   = (int*)alloc(4);
    int*  gcur   = (int*)alloc(256 * 4);
    int2* rpe    = (int2*)alloc((size_t)N * 8);
    int*  srcs   = (int*)alloc((size_t)NB * BCAP * 4);
    int2* binned = (int2*)alloc((size_t)NB * BCAP * 8);
    unsigned short* xb   = (unsigned short*)alloc((size_t)N * FD * 2);
    unsigned short* hb1  = (unsigned short*)alloc((size_t)N * FD * 2);
    unsigned short* hb2  = (unsigned short*)alloc((size_t)N * FD * 2);
    unsigned short* aggb = (unsigned short*)alloc((size_t)N * FD * 2);
    unsigned short* Wp   = (unsigned short*)alloc((size_t)6 * FD * FD * 2);
    (void)ws_size; (void)n_in; (void)out_size;

    int n4 = N * FD / 4;
    int nCvt = (n4 + 255) / 256;
    prep_k<<<nCvt + 384 + 1, 256, 0, stream>>>(
        (const unsigned int*)d_in[1], flag, gcur, x, xb, n4,
        W1r, W1o, W2r, W2o, W3r, W3o, Wp, nCvt, E);
    bin_k<<<(E + 8191) / 8192, 512, 0, stream>>>(d_in[1], flag, gcur, binned, E);
    csr_k<<<NB, 256, 0, stream>>>(binned, gcur, rpe, srcs, N);

    const int stride = FD * FD;
    int ablocks = (N + 3) / 4;
    int gblocks = (N + 31) / 32;

    aggb_k<<<ablocks, 256, 0, stream>>>(xb, rpe, srcs, aggb, N);
    mgemm_k<1><<<gblocks, 256, 0, stream>>>(aggb, xb, Wp + 0 * stride, Wp + 1 * stride, b1, hb1, N, 1);

    aggb_k<<<ablocks, 256, 0, stream>>>(hb1, rpe, srcs, aggb, N);
    mgemm_k<1><<<gblocks, 256, 0, stream>>>(aggb, hb1, Wp + 2 * stride, Wp + 3 * stride, b2, hb2, N, 1);

    aggb_k<<<ablocks, 256, 0, stream>>>(hb2, rpe, srcs, aggb, N);
    mgemm_k<0><<<gblocks, 256, 0, stream>>>(aggb, hb2, Wp + 4 * stride, Wp + 5 * stride, b3, d_out, N, 0);
}